// Round 16
// baseline (704.036 us; speedup 1.0000x reference)
//
#include <hip/hip_runtime.h>
#include <hip/hip_bf16.h>
#include <stdint.h>

// Problem constants
#define S_DIM 512
#define N_DIM 768
#define CMd   64
#define CZd   128
#define Hd    8
#define Dd    32
#define HDd   256

typedef float          f32x4  __attribute__((ext_vector_type(4)));
typedef __bf16         bf16x8 __attribute__((ext_vector_type(8)));
typedef unsigned int   u32x4  __attribute__((ext_vector_type(4)));
typedef unsigned int   u32x2  __attribute__((ext_vector_type(2)));
typedef unsigned short u16x8  __attribute__((ext_vector_type(8)));

__device__ __forceinline__ unsigned short f2bf(float f) {
  __bf16 h = (__bf16)f;
  return __builtin_bit_cast(unsigned short, h);
}
__device__ __forceinline__ float bf2f(unsigned short u) {
  unsigned int x = ((unsigned int)u) << 16;
  return __builtin_bit_cast(float, x);
}
__device__ __forceinline__ float sigmoidf_(float x) {
  return 1.f / (1.f + __expf(-x));
}

// ---------------------------------------------------------------------------
// K0: weight prep. WBT[j][c] = (j<256? wm[c][j] : wg[c][j-256]) bf16 (512x64)
//     woT[c][k]  = wo[k][c] bf16 (64x256)
// ---------------------------------------------------------------------------
__global__ __launch_bounds__(256) void k0_prep(const float* __restrict__ wm,
                                               const float* __restrict__ wg,
                                               const float* __restrict__ wo,
                                               unsigned short* __restrict__ WBT,
                                               unsigned short* __restrict__ woT) {
  int t = blockIdx.x * 256 + threadIdx.x;
  if (t < 512 * 64) {
    int j = t >> 6, c = t & 63;
    float v = (j < 256) ? wm[c * 256 + j] : wg[c * 256 + (j - 256)];
    WBT[t] = f2bf(v);
  }
  if (t < 64 * 256) {
    int c = t >> 8, k = t & 255;
    woT[t] = f2bf(wo[k * 64 + c]);
  }
}

// ---------------------------------------------------------------------------
// K1: LN(z) + b[p][h][q] = zn . wz   (wave handles 8 rows, 8 lanes/row)
// ---------------------------------------------------------------------------
__global__ __launch_bounds__(256) void k1_zln_b(const float* __restrict__ z,
                                                const float* __restrict__ nzw,
                                                const float* __restrict__ nzb,
                                                const float* __restrict__ wz,
                                                float* __restrict__ b_e) {
  __shared__ float wzT[8][128];
  int t = threadIdx.x;
  for (int i = t; i < 1024; i += 256) {
    int h = i >> 7, c = i & 127;
    wzT[h][c] = wz[c * 8 + h];
  }
  __syncthreads();

  int lane = t & 63, w = t >> 6;
  int sub = lane & 7;       // c-chunk (16 floats each)
  int rloc = lane >> 3;     // row within wave
  int p = blockIdx.y;
  int q = blockIdx.x * 32 + w * 8 + rloc;

  const float* zr = z + ((size_t)p * N_DIM + q) * CZd + sub * 16;
  f32x4 v[4];
#pragma unroll
  for (int j = 0; j < 4; j++) v[j] = *(const f32x4*)(zr + 4 * j);

  float s1 = 0.f, s2 = 0.f;
#pragma unroll
  for (int j = 0; j < 4; j++)
#pragma unroll
    for (int e = 0; e < 4; e++) { float x = v[j][e]; s1 += x; s2 += x * x; }
  s1 += __shfl_xor(s1, 1); s2 += __shfl_xor(s2, 1);
  s1 += __shfl_xor(s1, 2); s2 += __shfl_xor(s2, 2);
  s1 += __shfl_xor(s1, 4); s2 += __shfl_xor(s2, 4);
  float mean = s1 * (1.f / 128.f);
  float var  = s2 * (1.f / 128.f) - mean * mean;
  float rstd = rsqrtf(var + 1e-5f);

  const float* wp = nzw + sub * 16;
  const float* bp = nzb + sub * 16;
  float zn[16];
#pragma unroll
  for (int j = 0; j < 4; j++) {
    f32x4 wv = *(const f32x4*)(wp + 4 * j);
    f32x4 bv = *(const f32x4*)(bp + 4 * j);
#pragma unroll
    for (int e = 0; e < 4; e++)
      zn[j * 4 + e] = (v[j][e] - mean) * rstd * wv[e] + bv[e];
  }

  float accb[8];
#pragma unroll
  for (int h = 0; h < 8; h++) {
    const f32x4* wr = (const f32x4*)&wzT[h][sub * 16];
    float a = 0.f;
#pragma unroll
    for (int j = 0; j < 4; j++) {
      f32x4 ww = wr[j];
#pragma unroll
      for (int e = 0; e < 4; e++) a += zn[j * 4 + e] * ww[e];
    }
    accb[h] = a;
  }
#pragma unroll
  for (int mask = 1; mask <= 4; mask <<= 1)
#pragma unroll
    for (int h = 0; h < 8; h++) accb[h] += __shfl_xor(accb[h], mask);

  float outv = accb[0];
#pragma unroll
  for (int h = 1; h < 8; h++) outv = (sub == h) ? accb[h] : outv;
  b_e[((size_t)p * 8 + sub) * 768 + q] = outv;
}

// ---------------------------------------------------------------------------
// K1b: per (p,h) row: M = max_q b, invs = 1/sum(exp(b-M)). No write-back of
//      exp — k1b2 recomputes it (identical f32 ops on identical bits).
// ---------------------------------------------------------------------------
__global__ __launch_bounds__(256) void k1b_softmax(const float* __restrict__ b_e,
                                                   float* __restrict__ Ms,
                                                   float* __restrict__ invs) {
  int row = blockIdx.x;
  int t = threadIdx.x;
  const float* base = b_e + (size_t)row * 768;
  float x0 = base[t], x1 = base[t + 256], x2 = base[t + 512];
  __shared__ float red[256];
  red[t] = fmaxf(x0, fmaxf(x1, x2));
  __syncthreads();
  for (int o = 128; o > 0; o >>= 1) {
    if (t < o) red[t] = fmaxf(red[t], red[t + o]);
    __syncthreads();
  }
  float M = red[0];
  __syncthreads();
  float e0 = __expf(x0 - M), e1 = __expf(x1 - M), e2 = __expf(x2 - M);
  red[t] = e0 + e1 + e2;
  __syncthreads();
  for (int o = 128; o > 0; o >>= 1) {
    if (t < o) red[t] += red[t + o];
    __syncthreads();
  }
  if (t == 0) { Ms[row] = M; invs[row] = 1.0f / red[0]; }
}

// ---------------------------------------------------------------------------
// K1b2: exp + scale + transpose -> Aw[h][q][p] bf16
// ---------------------------------------------------------------------------
__global__ __launch_bounds__(256) void k1b2_transpose(const float* __restrict__ b_e,
                                                      const float* __restrict__ Ms,
                                                      const float* __restrict__ invs,
                                                      unsigned short* __restrict__ Aw) {
  int t = threadIdx.x;
  int q0 = blockIdx.x * 64, p0 = blockIdx.y * 64, h = blockIdx.z;
  __shared__ unsigned short T[64][65];
  int i = t >> 2, ch = t & 3;
  size_t rowid = (size_t)(p0 + i) * 8 + h;
  const float* src = b_e + rowid * 768 + q0 + ch * 16;
  float M = Ms[rowid];
  float inv = invs[rowid];
#pragma unroll
  for (int jj = 0; jj < 16; jj += 4) {
    f32x4 v = *(const f32x4*)(src + jj);
#pragma unroll
    for (int e = 0; e < 4; e++)
      T[i][ch * 16 + jj + e] = f2bf(__expf(v[e] - M) * inv);
  }
  __syncthreads();
  int j = i;  // output q-row within tile
  unsigned short outv[16];
#pragma unroll
  for (int ii = 0; ii < 16; ii++) outv[ii] = T[ch * 16 + ii][j];
  unsigned short* dst = Aw + ((size_t)h * 768 + q0 + j) * 768 + p0 + ch * 16;
  *(u32x4*)(dst)     = *(u32x4*)(outv);
  *(u32x4*)(dst + 8) = *(u32x4*)(outv + 8);
}

// ---------------------------------------------------------------------------
// K2: LN(m) + V/G dual GEMM (K=64), S-LOOP x8: stage weights ONCE per block.
//     Same arithmetic/stores as proven v1 — values bit-identical.
// ---------------------------------------------------------------------------
__global__ __launch_bounds__(256) void k2_mln_vg(const float* __restrict__ mp,
                                                 const float* __restrict__ nmw,
                                                 const float* __restrict__ nmb,
                                                 const unsigned short* __restrict__ WBT,
                                                 unsigned short* __restrict__ VT,
                                                 unsigned short* __restrict__ G) {
  __shared__ unsigned short WBs[512 * 64];
  __shared__ unsigned short As[64 * 64];
  int t = threadIdx.x;
  int p0 = blockIdx.x * 64;

  // stage weights once (swizzled: ushort-chunk idx ^ (row&7))
#pragma unroll
  for (int it = 0; it < 16; it++) {
    int cid = t + it * 256;
    int row = cid >> 3, ch = cid & 7;
    u32x4 v = *(const u32x4*)(WBT + row * 64 + ch * 8);
    *(u32x4*)(WBs + row * 64 + ((ch * 8) ^ ((row & 7) << 3))) = v;
  }

  int lane = t & 63, w = t >> 6;
  int n0 = w * 128;
  int lr = lane & 15, lk8 = (lane >> 4) * 8;
  f32x4 zero = {0.f, 0.f, 0.f, 0.f};

#pragma unroll 1
  for (int si = 0; si < 8; si++) {
    int s = blockIdx.y * 8 + si;

    // LN of 64 m-rows (4 lanes per row)
    {
      int row = t >> 2, qt = t & 3;
      const float* mr = mp + ((size_t)s * N_DIM + p0 + row) * CMd + qt * 16;
      f32x4 v[4];
#pragma unroll
      for (int j = 0; j < 4; j++) v[j] = *(const f32x4*)(mr + 4 * j);
      float s1 = 0.f, s2 = 0.f;
#pragma unroll
      for (int j = 0; j < 4; j++)
#pragma unroll
        for (int e = 0; e < 4; e++) { float x = v[j][e]; s1 += x; s2 += x * x; }
      s1 += __shfl_xor(s1, 1); s2 += __shfl_xor(s2, 1);
      s1 += __shfl_xor(s1, 2); s2 += __shfl_xor(s2, 2);
      float mean = s1 * (1.f / 64.f);
      float var  = s2 * (1.f / 64.f) - mean * mean;
      float rstd = rsqrtf(var + 1e-5f);
      unsigned short o[16];
#pragma unroll
      for (int j = 0; j < 4; j++) {
        f32x4 wv = *(const f32x4*)(nmw + qt * 16 + 4 * j);
        f32x4 bv = *(const f32x4*)(nmb + qt * 16 + 4 * j);
#pragma unroll
        for (int e = 0; e < 4; e++)
          o[j * 4 + e] = f2bf((v[j][e] - mean) * rstd * wv[e] + bv[e]);
      }
      int k0 = qt * 16;
      *(u32x4*)(As + row * 64 + ((k0) ^ ((row & 7) << 3)))     = *(u32x4*)(o);
      *(u32x4*)(As + row * 64 + ((k0 + 8) ^ ((row & 7) << 3))) = *(u32x4*)(o + 8);
    }
    __syncthreads();   // As (and, on si=0, WBs) visible to all waves

    f32x4 acc[4][8];
#pragma unroll
    for (int i = 0; i < 4; i++)
#pragma unroll
      for (int j = 0; j < 8; j++) acc[i][j] = zero;

#pragma unroll
    for (int kk = 0; kk < 2; kk++) {
      bf16x8 bfr[8];
#pragma unroll
      for (int nt = 0; nt < 8; nt++) {
        int r = n0 + nt * 16 + lr;
        bfr[nt] = *(const bf16x8*)(WBs + r * 64 + ((kk * 32 + lk8) ^ ((r & 7) << 3)));
      }
#pragma unroll
      for (int mt = 0; mt < 4; mt++) {
        int ar = mt * 16 + lr;
        bf16x8 a = *(const bf16x8*)(As + ar * 64 + ((kk * 32 + lk8) ^ ((ar & 7) << 3)));
#pragma unroll
        for (int nt = 0; nt < 8; nt++)
          acc[mt][nt] = __builtin_amdgcn_mfma_f32_16x16x32_bf16(a, bfr[nt], acc[mt][nt], 0, 0, 0);
      }
    }

    // epilogue (identical stores to v1)
#pragma unroll
    for (int mt = 0; mt < 4; mt++)
#pragma unroll
      for (int nt = 0; nt < 8; nt++) {
        int j = n0 + nt * 16 + lr;
        int ploc = mt * 16 + (lane >> 4) * 4;
        if (j < 256) {
          int h = j >> 5, d = j & 31;
          unsigned short pk[4];
#pragma unroll
          for (int r = 0; r < 4; r++) pk[r] = f2bf(acc[mt][nt][r]);
          *(u32x2*)(VT + ((size_t)h * 16384 + s * 32 + d) * 768 + p0 + ploc) = *(u32x2*)pk;
        } else {
          int jj = j - 256;
#pragma unroll
          for (int r = 0; r < 4; r++)
            G[((size_t)s * 768 + p0 + ploc + r) * 256 + jj] = f2bf(sigmoidf_(acc[mt][nt][r]));
        }
      }
    __syncthreads();   // all MFMA reads of As done before next iter's LN writes
  }
}

// ---------------------------------------------------------------------------
// K3: per-head GEMM  O[q][(s,d)] = sum_p Aw[h][q][p] * VT[h][sd][p]
//     128x128 tile, BK=64, reg-staged LDS with DEPTH-2 register prefetch:
//     two K-tiles in flight in VGPRs; same write->barrier->read->barrier LDS
//     discipline; compiler dep-tracking orders loads vs LDS writes. No async.
// ---------------------------------------------------------------------------
__global__ __launch_bounds__(256) void k3_gemm(const unsigned short* __restrict__ Aw,
                                               const unsigned short* __restrict__ VT,
                                               unsigned short* __restrict__ O) {
  __shared__ unsigned short Asl[128 * 64];
  __shared__ unsigned short Bsl[128 * 64];
  int t = threadIdx.x;
  int flat = blockIdx.x;                   // 0..767
  int h = blockIdx.y;
  int f2 = (flat & 7) * 96 + (flat >> 3);  // XCD-contiguous remap (768 = 8*96)
  int mt_b = f2 % 6, nt_b = f2 / 6;
  int q0 = mt_b * 128, n0 = nt_b * 128;

  const unsigned short* Ab = Aw + (size_t)h * 768 * 768 + (size_t)q0 * 768;
  const unsigned short* Bb = VT + (size_t)h * 16384 * 768 + (size_t)n0 * 768;

  int lane = t & 63, w = t >> 6;
  int wr = (w >> 1) * 64, wc = (w & 1) * 64;
  int lr = lane & 15, lk8 = (lane >> 4) * 8;
  int ch = t & 7, r0 = t >> 3;

  u32x4 ra[2][4], rb[2][4];
#pragma unroll
  for (int b = 0; b < 2; b++)
#pragma unroll
    for (int it = 0; it < 4; it++) {
      int r = r0 + it * 32;
      ra[b][it] = *(const u32x4*)(Ab + (size_t)r * 768 + b * 64 + ch * 8);
      rb[b][it] = *(const u32x4*)(Bb + (size_t)r * 768 + b * 64 + ch * 8);
    }

  f32x4 zero = {0.f, 0.f, 0.f, 0.f};
  f32x4 acc[4][4];
#pragma unroll
  for (int i = 0; i < 4; i++)
#pragma unroll
    for (int j = 0; j < 4; j++) acc[i][j] = zero;

  for (int kt = 0; kt < 12; kt++) {
    int cur = kt & 1;
    // write tile kt (from regs) into LDS
#pragma unroll
    for (int it = 0; it < 4; it++) {
      int cid = t + it * 256;
      int row = cid >> 3, c = cid & 7;
      int idx = row * 64 + ((c * 8) ^ ((row & 7) << 3));
      *(u32x4*)(Asl + idx) = ra[cur][it];
      *(u32x4*)(Bsl + idx) = rb[cur][it];
    }
    __syncthreads();
    // issue loads for tile kt+2 into the slot just freed (2 phases to land)
    if (kt < 10) {
      int k0 = (kt + 2) * 64;
#pragma unroll
      for (int it = 0; it < 4; it++) {
        int r = r0 + it * 32;
        ra[cur][it] = *(const u32x4*)(Ab + (size_t)r * 768 + k0 + ch * 8);
        rb[cur][it] = *(const u32x4*)(Bb + (size_t)r * 768 + k0 + ch * 8);
      }
    }
#pragma unroll
    for (int kk = 0; kk < 2; kk++) {
      bf16x8 afr[4], bfr[4];
#pragma unroll
      for (int i = 0; i < 4; i++) {
        int arr = wr + i * 16 + lr;
        int brr = wc + i * 16 + lr;
        afr[i] = *(const bf16x8*)(Asl + arr * 64 + ((kk * 32 + lk8) ^ ((arr & 7) << 3)));
        bfr[i] = *(const bf16x8*)(Bsl + brr * 64 + ((kk * 32 + lk8) ^ ((brr & 7) << 3)));
      }
#pragma unroll
      for (int mt = 0; mt < 4; mt++)
#pragma unroll
        for (int nt = 0; nt < 4; nt++)
          acc[mt][nt] = __builtin_amdgcn_mfma_f32_16x16x32_bf16(afr[mt], bfr[nt], acc[mt][nt], 0, 0, 0);
    }
    __syncthreads();
  }

  // epilogue: O[s][q][h*32+d]
#pragma unroll
  for (int mt = 0; mt < 4; mt++)
#pragma unroll
    for (int nt = 0; nt < 4; nt++) {
      int q = q0 + wr + mt * 16 + (lane >> 4) * 4;
      int n = n0 + wc + nt * 16 + lr;
      int s_ = n >> 5, d = n & 31;
      size_t ob = ((size_t)s_ * 768 + q) * 256 + h * 32 + d;
#pragma unroll
      for (int r = 0; r < 4; r++)
        O[ob + (size_t)r * 256] = f2bf(acc[mt][nt][r]);
    }
}

// ---------------------------------------------------------------------------
// K4: out[s][q][c] = sum_hd (O*G)[s][q][hd] * woT[c][hd], S-LOOP x8:
//     stage woT ONCE per block, then loop 8 s values.
// ---------------------------------------------------------------------------
__global__ __launch_bounds__(256) void k4_out(const unsigned short* __restrict__ O,
                                              const unsigned short* __restrict__ G,
                                              const unsigned short* __restrict__ woT,
                                              float* __restrict__ out) {
  __shared__ unsigned short OGs[64 * 256];
  __shared__ unsigned short WOs[64 * 256];
  int t = threadIdx.x;
  int q0 = blockIdx.x * 64;

  // stage woT once: 64 rows x 32 chunks-of-8 (2048 chunks)
#pragma unroll
  for (int it = 0; it < 8; it++) {
    int cid = t + it * 256;
    int row = cid >> 5, ch = cid & 31;
    u32x4 v = *(const u32x4*)(woT + row * 256 + ch * 8);
    *(u32x4*)(WOs + row * 256 + ((ch * 8) ^ ((row & 7) << 3))) = v;
  }

  int lane = t & 63, w = t >> 6;
  int lr = lane & 15, lk8 = (lane >> 4) * 8;
  f32x4 zero = {0.f, 0.f, 0.f, 0.f};
  int i = t >> 2, c4 = t & 3;

#pragma unroll 1
  for (int si = 0; si < 8; si++) {
    int s = blockIdx.y * 8 + si;

    const unsigned short* Orow = O + ((size_t)s * 768 + q0 + i) * 256 + c4 * 64;
    const unsigned short* Grow = G + ((size_t)s * 768 + q0 + i) * 256 + c4 * 64;
#pragma unroll
    for (int jj = 0; jj < 8; jj++) {
      u16x8 ov = *(const u16x8*)(Orow + jj * 8);
      u16x8 gv = *(const u16x8*)(Grow + jj * 8);
      unsigned short pk[8];
#pragma unroll
      for (int e = 0; e < 8; e++) pk[e] = f2bf(bf2f(ov[e]) * bf2f(gv[e]));
      *(u32x4*)(OGs + i * 256 + ((c4 * 64 + jj * 8) ^ ((i & 7) << 3))) = *(u32x4*)pk;
    }
    __syncthreads();   // OGs (and, on si=0, WOs) visible

    f32x4 acc[4];
#pragma unroll
    for (int nt = 0; nt < 4; nt++) acc[nt] = zero;

#pragma unroll
    for (int kk = 0; kk < 8; kk++) {
      int ar = w * 16 + lr;
      bf16x8 a = *(const bf16x8*)(OGs + ar * 256 + ((kk * 32 + lk8) ^ ((ar & 7) << 3)));
#pragma unroll
      for (int nt = 0; nt < 4; nt++) {
        int br = nt * 16 + lr;
        bf16x8 b = *(const bf16x8*)(WOs + br * 256 + ((kk * 32 + lk8) ^ ((br & 7) << 3)));
        acc[nt] = __builtin_amdgcn_mfma_f32_16x16x32_bf16(a, b, acc[nt], 0, 0, 0);
      }
    }

#pragma unroll
    for (int nt = 0; nt < 4; nt++) {
      int q = q0 + w * 16 + (lane >> 4) * 4;
      int c = nt * 16 + lr;
      float* dst = out + ((size_t)s * 768 + q) * 64 + c;
#pragma unroll
      for (int r = 0; r < 4; r++) dst[(size_t)r * 64] = acc[nt][r];
    }
    __syncthreads();   // all MFMA reads of OGs done before next iter's writes
  }
}

// ---------------------------------------------------------------------------
extern "C" void kernel_launch(void* const* d_in, const int* in_sizes, int n_in,
                              void* d_out, int out_size, void* d_ws, size_t ws_size,
                              hipStream_t stream) {
  const float* m   = (const float*)d_in[0];
  const float* z   = (const float*)d_in[1];
  const float* nmw = (const float*)d_in[2];
  const float* nmb = (const float*)d_in[3];
  const float* nzw = (const float*)d_in[4];
  const float* nzb = (const float*)d_in[5];
  const float* wm  = (const float*)d_in[6];
  const float* wg  = (const float*)d_in[7];
  const float* wz  = (const float*)d_in[8];
  const float* wo  = (const float*)d_in[9];
  float* out = (float*)d_out;

  char* ws = (char*)d_ws;
  size_t off = 0;
  auto alloc = [&](size_t bytes) -> void* {
    void* p = ws + off;
    off += (bytes + 1023) & ~(size_t)1023;
    return p;
  };
  float*          b_e  = (float*)alloc((size_t)768 * 8 * 768 * 4);          // 18.9 MB
  float*          Ms   = (float*)alloc((size_t)768 * 8 * 4);
  float*          invs = (float*)alloc((size_t)768 * 8 * 4);
  unsigned short* Awt  = (unsigned short*)alloc((size_t)8 * 768 * 768 * 2); // 9.4 MB
  unsigned short* WBT  = (unsigned short*)alloc((size_t)512 * 64 * 2);
  unsigned short* woT  = (unsigned short*)alloc((size_t)64 * 256 * 2);
  unsigned short* VT   = (unsigned short*)alloc((size_t)8 * 16384 * 768 * 2);  // 201 MB
  unsigned short* G    = (unsigned short*)alloc((size_t)512 * 768 * 256 * 2);  // 201 MB
  unsigned short* O    = (unsigned short*)alloc((size_t)512 * 768 * 256 * 2);  // 201 MB
  if (ws_size < off) return;  // workspace too small: fail loudly (zero output)

  k0_prep<<<128, 256, 0, stream>>>(wm, wg, wo, WBT, woT);
  k1_zln_b<<<dim3(24, 768), 256, 0, stream>>>(z, nzw, nzb, wz, b_e);
  k1b_softmax<<<6144, 256, 0, stream>>>(b_e, Ms, invs);
  k1b2_transpose<<<dim3(12, 12, 8), 256, 0, stream>>>(b_e, Ms, invs, Awt);
  k2_mln_vg<<<dim3(12, 64), 256, 0, stream>>>(m, nmw, nmb, WBT, VT, G);
  k3_gemm<<<dim3(768, 8), 256, 0, stream>>>(Awt, VT, O);
  k4_out<<<dim3(12, 64), 256, 0, stream>>>(O, G, woT, out);
}

// Round 17
// 672.577 us; speedup vs baseline: 1.0468x; 1.0468x over previous
//
#include <hip/hip_runtime.h>
#include <hip/hip_bf16.h>
#include <stdint.h>

// Problem constants
#define S_DIM 512
#define N_DIM 768
#define CMd   64
#define CZd   128
#define Hd    8
#define Dd    32
#define HDd   256

typedef float          f32x4  __attribute__((ext_vector_type(4)));
typedef __bf16         bf16x8 __attribute__((ext_vector_type(8)));
typedef unsigned int   u32x4  __attribute__((ext_vector_type(4)));
typedef unsigned int   u32x2  __attribute__((ext_vector_type(2)));
typedef unsigned short u16x8  __attribute__((ext_vector_type(8)));

__device__ __forceinline__ unsigned short f2bf(float f) {
  __bf16 h = (__bf16)f;
  return __builtin_bit_cast(unsigned short, h);
}
__device__ __forceinline__ float bf2f(unsigned short u) {
  unsigned int x = ((unsigned int)u) << 16;
  return __builtin_bit_cast(float, x);
}
__device__ __forceinline__ float sigmoidf_(float x) {
  return 1.f / (1.f + __expf(-x));
}

// ---------------------------------------------------------------------------
// K0: weight prep. WBT[j][c] = (j<256? wm[c][j] : wg[c][j-256]) bf16 (512x64)
//     woT[c][k]  = wo[k][c] bf16 (64x256)
// ---------------------------------------------------------------------------
__global__ __launch_bounds__(256) void k0_prep(const float* __restrict__ wm,
                                               const float* __restrict__ wg,
                                               const float* __restrict__ wo,
                                               unsigned short* __restrict__ WBT,
                                               unsigned short* __restrict__ woT) {
  int t = blockIdx.x * 256 + threadIdx.x;
  if (t < 512 * 64) {
    int j = t >> 6, c = t & 63;
    float v = (j < 256) ? wm[c * 256 + j] : wg[c * 256 + (j - 256)];
    WBT[t] = f2bf(v);
  }
  if (t < 64 * 256) {
    int c = t >> 8, k = t & 255;
    woT[t] = f2bf(wo[k * 64 + c]);
  }
}

// ---------------------------------------------------------------------------
// K1: LN(z) + b[p][h][q] = zn . wz   (wave handles 8 rows, 8 lanes/row)
// ---------------------------------------------------------------------------
__global__ __launch_bounds__(256) void k1_zln_b(const float* __restrict__ z,
                                                const float* __restrict__ nzw,
                                                const float* __restrict__ nzb,
                                                const float* __restrict__ wz,
                                                float* __restrict__ b_e) {
  __shared__ float wzT[8][128];
  int t = threadIdx.x;
  for (int i = t; i < 1024; i += 256) {
    int h = i >> 7, c = i & 127;
    wzT[h][c] = wz[c * 8 + h];
  }
  __syncthreads();

  int lane = t & 63, w = t >> 6;
  int sub = lane & 7;       // c-chunk (16 floats each)
  int rloc = lane >> 3;     // row within wave
  int p = blockIdx.y;
  int q = blockIdx.x * 32 + w * 8 + rloc;

  const float* zr = z + ((size_t)p * N_DIM + q) * CZd + sub * 16;
  f32x4 v[4];
#pragma unroll
  for (int j = 0; j < 4; j++) v[j] = *(const f32x4*)(zr + 4 * j);

  float s1 = 0.f, s2 = 0.f;
#pragma unroll
  for (int j = 0; j < 4; j++)
#pragma unroll
    for (int e = 0; e < 4; e++) { float x = v[j][e]; s1 += x; s2 += x * x; }
  s1 += __shfl_xor(s1, 1); s2 += __shfl_xor(s2, 1);
  s1 += __shfl_xor(s1, 2); s2 += __shfl_xor(s2, 2);
  s1 += __shfl_xor(s1, 4); s2 += __shfl_xor(s2, 4);
  float mean = s1 * (1.f / 128.f);
  float var  = s2 * (1.f / 128.f) - mean * mean;
  float rstd = rsqrtf(var + 1e-5f);

  const float* wp = nzw + sub * 16;
  const float* bp = nzb + sub * 16;
  float zn[16];
#pragma unroll
  for (int j = 0; j < 4; j++) {
    f32x4 wv = *(const f32x4*)(wp + 4 * j);
    f32x4 bv = *(const f32x4*)(bp + 4 * j);
#pragma unroll
    for (int e = 0; e < 4; e++)
      zn[j * 4 + e] = (v[j][e] - mean) * rstd * wv[e] + bv[e];
  }

  float accb[8];
#pragma unroll
  for (int h = 0; h < 8; h++) {
    const f32x4* wr = (const f32x4*)&wzT[h][sub * 16];
    float a = 0.f;
#pragma unroll
    for (int j = 0; j < 4; j++) {
      f32x4 ww = wr[j];
#pragma unroll
      for (int e = 0; e < 4; e++) a += zn[j * 4 + e] * ww[e];
    }
    accb[h] = a;
  }
#pragma unroll
  for (int mask = 1; mask <= 4; mask <<= 1)
#pragma unroll
    for (int h = 0; h < 8; h++) accb[h] += __shfl_xor(accb[h], mask);

  float outv = accb[0];
#pragma unroll
  for (int h = 1; h < 8; h++) outv = (sub == h) ? accb[h] : outv;
  b_e[((size_t)p * 8 + sub) * 768 + q] = outv;
}

// ---------------------------------------------------------------------------
// K1b: per (p,h) row: M = max_q b, invs = 1/sum(exp(b-M)). No write-back of
//      exp — k1b2 recomputes it (identical f32 ops on identical bits).
// ---------------------------------------------------------------------------
__global__ __launch_bounds__(256) void k1b_softmax(const float* __restrict__ b_e,
                                                   float* __restrict__ Ms,
                                                   float* __restrict__ invs) {
  int row = blockIdx.x;
  int t = threadIdx.x;
  const float* base = b_e + (size_t)row * 768;
  float x0 = base[t], x1 = base[t + 256], x2 = base[t + 512];
  __shared__ float red[256];
  red[t] = fmaxf(x0, fmaxf(x1, x2));
  __syncthreads();
  for (int o = 128; o > 0; o >>= 1) {
    if (t < o) red[t] = fmaxf(red[t], red[t + o]);
    __syncthreads();
  }
  float M = red[0];
  __syncthreads();
  float e0 = __expf(x0 - M), e1 = __expf(x1 - M), e2 = __expf(x2 - M);
  red[t] = e0 + e1 + e2;
  __syncthreads();
  for (int o = 128; o > 0; o >>= 1) {
    if (t < o) red[t] += red[t + o];
    __syncthreads();
  }
  if (t == 0) { Ms[row] = M; invs[row] = 1.0f / red[0]; }
}

// ---------------------------------------------------------------------------
// K1b2: exp + scale + transpose -> Aw[h][q][p] bf16
// ---------------------------------------------------------------------------
__global__ __launch_bounds__(256) void k1b2_transpose(const float* __restrict__ b_e,
                                                      const float* __restrict__ Ms,
                                                      const float* __restrict__ invs,
                                                      unsigned short* __restrict__ Aw) {
  int t = threadIdx.x;
  int q0 = blockIdx.x * 64, p0 = blockIdx.y * 64, h = blockIdx.z;
  __shared__ unsigned short T[64][65];
  int i = t >> 2, ch = t & 3;
  size_t rowid = (size_t)(p0 + i) * 8 + h;
  const float* src = b_e + rowid * 768 + q0 + ch * 16;
  float M = Ms[rowid];
  float inv = invs[rowid];
#pragma unroll
  for (int jj = 0; jj < 16; jj += 4) {
    f32x4 v = *(const f32x4*)(src + jj);
#pragma unroll
    for (int e = 0; e < 4; e++)
      T[i][ch * 16 + jj + e] = f2bf(__expf(v[e] - M) * inv);
  }
  __syncthreads();
  int j = i;  // output q-row within tile
  unsigned short outv[16];
#pragma unroll
  for (int ii = 0; ii < 16; ii++) outv[ii] = T[ch * 16 + ii][j];
  unsigned short* dst = Aw + ((size_t)h * 768 + q0 + j) * 768 + p0 + ch * 16;
  *(u32x4*)(dst)     = *(u32x4*)(outv);
  *(u32x4*)(dst + 8) = *(u32x4*)(outv + 8);
}

// ---------------------------------------------------------------------------
// K2: LN(m) + V/G dual GEMM (K=64), S-LOOP x8: stage weights ONCE per block.
//     Same arithmetic/stores as proven v1 — values bit-identical.
// ---------------------------------------------------------------------------
__global__ __launch_bounds__(256) void k2_mln_vg(const float* __restrict__ mp,
                                                 const float* __restrict__ nmw,
                                                 const float* __restrict__ nmb,
                                                 const unsigned short* __restrict__ WBT,
                                                 unsigned short* __restrict__ VT,
                                                 unsigned short* __restrict__ G) {
  __shared__ unsigned short WBs[512 * 64];
  __shared__ unsigned short As[64 * 64];
  int t = threadIdx.x;
  int p0 = blockIdx.x * 64;

  // stage weights once (swizzled: ushort-chunk idx ^ (row&7))
#pragma unroll
  for (int it = 0; it < 16; it++) {
    int cid = t + it * 256;
    int row = cid >> 3, ch = cid & 7;
    u32x4 v = *(const u32x4*)(WBT + row * 64 + ch * 8);
    *(u32x4*)(WBs + row * 64 + ((ch * 8) ^ ((row & 7) << 3))) = v;
  }

  int lane = t & 63, w = t >> 6;
  int n0 = w * 128;
  int lr = lane & 15, lk8 = (lane >> 4) * 8;
  f32x4 zero = {0.f, 0.f, 0.f, 0.f};

#pragma unroll 1
  for (int si = 0; si < 8; si++) {
    int s = blockIdx.y * 8 + si;

    // LN of 64 m-rows (4 lanes per row)
    {
      int row = t >> 2, qt = t & 3;
      const float* mr = mp + ((size_t)s * N_DIM + p0 + row) * CMd + qt * 16;
      f32x4 v[4];
#pragma unroll
      for (int j = 0; j < 4; j++) v[j] = *(const f32x4*)(mr + 4 * j);
      float s1 = 0.f, s2 = 0.f;
#pragma unroll
      for (int j = 0; j < 4; j++)
#pragma unroll
        for (int e = 0; e < 4; e++) { float x = v[j][e]; s1 += x; s2 += x * x; }
      s1 += __shfl_xor(s1, 1); s2 += __shfl_xor(s2, 1);
      s1 += __shfl_xor(s1, 2); s2 += __shfl_xor(s2, 2);
      float mean = s1 * (1.f / 64.f);
      float var  = s2 * (1.f / 64.f) - mean * mean;
      float rstd = rsqrtf(var + 1e-5f);
      unsigned short o[16];
#pragma unroll
      for (int j = 0; j < 4; j++) {
        f32x4 wv = *(const f32x4*)(nmw + qt * 16 + 4 * j);
        f32x4 bv = *(const f32x4*)(nmb + qt * 16 + 4 * j);
#pragma unroll
        for (int e = 0; e < 4; e++)
          o[j * 4 + e] = f2bf((v[j][e] - mean) * rstd * wv[e] + bv[e]);
      }
      int k0 = qt * 16;
      *(u32x4*)(As + row * 64 + ((k0) ^ ((row & 7) << 3)))     = *(u32x4*)(o);
      *(u32x4*)(As + row * 64 + ((k0 + 8) ^ ((row & 7) << 3))) = *(u32x4*)(o + 8);
    }
    __syncthreads();   // As (and, on si=0, WBs) visible to all waves

    f32x4 acc[4][8];
#pragma unroll
    for (int i = 0; i < 4; i++)
#pragma unroll
      for (int j = 0; j < 8; j++) acc[i][j] = zero;

#pragma unroll
    for (int kk = 0; kk < 2; kk++) {
      bf16x8 bfr[8];
#pragma unroll
      for (int nt = 0; nt < 8; nt++) {
        int r = n0 + nt * 16 + lr;
        bfr[nt] = *(const bf16x8*)(WBs + r * 64 + ((kk * 32 + lk8) ^ ((r & 7) << 3)));
      }
#pragma unroll
      for (int mt = 0; mt < 4; mt++) {
        int ar = mt * 16 + lr;
        bf16x8 a = *(const bf16x8*)(As + ar * 64 + ((kk * 32 + lk8) ^ ((ar & 7) << 3)));
#pragma unroll
        for (int nt = 0; nt < 8; nt++)
          acc[mt][nt] = __builtin_amdgcn_mfma_f32_16x16x32_bf16(a, bfr[nt], acc[mt][nt], 0, 0, 0);
      }
    }

    // epilogue (identical stores to v1)
#pragma unroll
    for (int mt = 0; mt < 4; mt++)
#pragma unroll
      for (int nt = 0; nt < 8; nt++) {
        int j = n0 + nt * 16 + lr;
        int ploc = mt * 16 + (lane >> 4) * 4;
        if (j < 256) {
          int h = j >> 5, d = j & 31;
          unsigned short pk[4];
#pragma unroll
          for (int r = 0; r < 4; r++) pk[r] = f2bf(acc[mt][nt][r]);
          *(u32x2*)(VT + ((size_t)h * 16384 + s * 32 + d) * 768 + p0 + ploc) = *(u32x2*)pk;
        } else {
          int jj = j - 256;
#pragma unroll
          for (int r = 0; r < 4; r++)
            G[((size_t)s * 768 + p0 + ploc + r) * 256 + jj] = f2bf(sigmoidf_(acc[mt][nt][r]));
        }
      }
    __syncthreads();   // all MFMA reads of As done before next iter's LN writes
  }
}

// ---------------------------------------------------------------------------
// K3: per-head GEMM  O[q][(s,d)] = sum_p Aw[h][q][p] * VT[h][sd][p]
//     128x128 tile, BK=64, reg-staged LDS, swizzled, XCD-aware remap.
//     (R15-exact: single-depth prefetch, VGPR 80 — the proven configuration)
// ---------------------------------------------------------------------------
__global__ __launch_bounds__(256) void k3_gemm(const unsigned short* __restrict__ Aw,
                                               const unsigned short* __restrict__ VT,
                                               unsigned short* __restrict__ O) {
  __shared__ unsigned short Asl[128 * 64];
  __shared__ unsigned short Bsl[128 * 64];
  int t = threadIdx.x;
  int flat = blockIdx.x;                   // 0..767
  int h = blockIdx.y;
  int f2 = (flat & 7) * 96 + (flat >> 3);  // XCD-contiguous remap (768 = 8*96)
  int mt_b = f2 % 6, nt_b = f2 / 6;
  int q0 = mt_b * 128, n0 = nt_b * 128;

  const unsigned short* Ab = Aw + (size_t)h * 768 * 768 + (size_t)q0 * 768;
  const unsigned short* Bb = VT + (size_t)h * 16384 * 768 + (size_t)n0 * 768;

  int lane = t & 63, w = t >> 6;
  int wr = (w >> 1) * 64, wc = (w & 1) * 64;
  int lr = lane & 15, lk8 = (lane >> 4) * 8;
  int ch = t & 7, r0 = t >> 3;

  u32x4 ra[4], rb[4];
#pragma unroll
  for (int it = 0; it < 4; it++) {
    int r = r0 + it * 32;
    ra[it] = *(const u32x4*)(Ab + (size_t)r * 768 + ch * 8);
    rb[it] = *(const u32x4*)(Bb + (size_t)r * 768 + ch * 8);
  }

  f32x4 zero = {0.f, 0.f, 0.f, 0.f};
  f32x4 acc[4][4];
#pragma unroll
  for (int i = 0; i < 4; i++)
#pragma unroll
    for (int j = 0; j < 4; j++) acc[i][j] = zero;

  for (int kt = 0; kt < 12; kt++) {
#pragma unroll
    for (int it = 0; it < 4; it++) {
      int cid = t + it * 256;
      int row = cid >> 3, c = cid & 7;
      int idx = row * 64 + ((c * 8) ^ ((row & 7) << 3));
      *(u32x4*)(Asl + idx) = ra[it];
      *(u32x4*)(Bsl + idx) = rb[it];
    }
    __syncthreads();
    if (kt < 11) {
      int k0 = (kt + 1) * 64;
#pragma unroll
      for (int it = 0; it < 4; it++) {
        int r = r0 + it * 32;
        ra[it] = *(const u32x4*)(Ab + (size_t)r * 768 + k0 + ch * 8);
        rb[it] = *(const u32x4*)(Bb + (size_t)r * 768 + k0 + ch * 8);
      }
    }
#pragma unroll
    for (int kk = 0; kk < 2; kk++) {
      bf16x8 afr[4], bfr[4];
#pragma unroll
      for (int i = 0; i < 4; i++) {
        int arr = wr + i * 16 + lr;
        int brr = wc + i * 16 + lr;
        afr[i] = *(const bf16x8*)(Asl + arr * 64 + ((kk * 32 + lk8) ^ ((arr & 7) << 3)));
        bfr[i] = *(const bf16x8*)(Bsl + brr * 64 + ((kk * 32 + lk8) ^ ((brr & 7) << 3)));
      }
#pragma unroll
      for (int mt = 0; mt < 4; mt++)
#pragma unroll
        for (int nt = 0; nt < 4; nt++)
          acc[mt][nt] = __builtin_amdgcn_mfma_f32_16x16x32_bf16(afr[mt], bfr[nt], acc[mt][nt], 0, 0, 0);
    }
    __syncthreads();
  }

  // epilogue: O[s][q][h*32+d]
#pragma unroll
  for (int mt = 0; mt < 4; mt++)
#pragma unroll
    for (int nt = 0; nt < 4; nt++) {
      int q = q0 + wr + mt * 16 + (lane >> 4) * 4;
      int n = n0 + wc + nt * 16 + lr;
      int s_ = n >> 5, d = n & 31;
      size_t ob = ((size_t)s_ * 768 + q) * 256 + h * 32 + d;
#pragma unroll
      for (int r = 0; r < 4; r++)
        O[ob + (size_t)r * 256] = f2bf(acc[mt][nt][r]);
    }
}

// ---------------------------------------------------------------------------
// K4: out[s][q][c] = sum_hd (O*G)[s][q][hd] * woT[c][hd], S-LOOP x8:
//     stage woT ONCE per block, then loop 8 s values.
// ---------------------------------------------------------------------------
__global__ __launch_bounds__(256) void k4_out(const unsigned short* __restrict__ O,
                                              const unsigned short* __restrict__ G,
                                              const unsigned short* __restrict__ woT,
                                              float* __restrict__ out) {
  __shared__ unsigned short OGs[64 * 256];
  __shared__ unsigned short WOs[64 * 256];
  int t = threadIdx.x;
  int q0 = blockIdx.x * 64;

  // stage woT once: 64 rows x 32 chunks-of-8 (2048 chunks)
#pragma unroll
  for (int it = 0; it < 8; it++) {
    int cid = t + it * 256;
    int row = cid >> 5, ch = cid & 31;
    u32x4 v = *(const u32x4*)(woT + row * 256 + ch * 8);
    *(u32x4*)(WOs + row * 256 + ((ch * 8) ^ ((row & 7) << 3))) = v;
  }

  int lane = t & 63, w = t >> 6;
  int lr = lane & 15, lk8 = (lane >> 4) * 8;
  f32x4 zero = {0.f, 0.f, 0.f, 0.f};
  int i = t >> 2, c4 = t & 3;

#pragma unroll 1
  for (int si = 0; si < 8; si++) {
    int s = blockIdx.y * 8 + si;

    const unsigned short* Orow = O + ((size_t)s * 768 + q0 + i) * 256 + c4 * 64;
    const unsigned short* Grow = G + ((size_t)s * 768 + q0 + i) * 256 + c4 * 64;
#pragma unroll
    for (int jj = 0; jj < 8; jj++) {
      u16x8 ov = *(const u16x8*)(Orow + jj * 8);
      u16x8 gv = *(const u16x8*)(Grow + jj * 8);
      unsigned short pk[8];
#pragma unroll
      for (int e = 0; e < 8; e++) pk[e] = f2bf(bf2f(ov[e]) * bf2f(gv[e]));
      *(u32x4*)(OGs + i * 256 + ((c4 * 64 + jj * 8) ^ ((i & 7) << 3))) = *(u32x4*)pk;
    }
    __syncthreads();   // OGs (and, on si=0, WOs) visible

    f32x4 acc[4];
#pragma unroll
    for (int nt = 0; nt < 4; nt++) acc[nt] = zero;

#pragma unroll
    for (int kk = 0; kk < 8; kk++) {
      int ar = w * 16 + lr;
      bf16x8 a = *(const bf16x8*)(OGs + ar * 256 + ((kk * 32 + lk8) ^ ((ar & 7) << 3)));
#pragma unroll
      for (int nt = 0; nt < 4; nt++) {
        int br = nt * 16 + lr;
        bf16x8 b = *(const bf16x8*)(WOs + br * 256 + ((kk * 32 + lk8) ^ ((br & 7) << 3)));
        acc[nt] = __builtin_amdgcn_mfma_f32_16x16x32_bf16(a, b, acc[nt], 0, 0, 0);
      }
    }

#pragma unroll
    for (int nt = 0; nt < 4; nt++) {
      int q = q0 + w * 16 + (lane >> 4) * 4;
      int c = nt * 16 + lr;
      float* dst = out + ((size_t)s * 768 + q) * 64 + c;
#pragma unroll
      for (int r = 0; r < 4; r++) dst[(size_t)r * 64] = acc[nt][r];
    }
    __syncthreads();   // all MFMA reads of OGs done before next iter's writes
  }
}

// ---------------------------------------------------------------------------
extern "C" void kernel_launch(void* const* d_in, const int* in_sizes, int n_in,
                              void* d_out, int out_size, void* d_ws, size_t ws_size,
                              hipStream_t stream) {
  const float* m   = (const float*)d_in[0];
  const float* z   = (const float*)d_in[1];
  const float* nmw = (const float*)d_in[2];
  const float* nmb = (const float*)d_in[3];
  const float* nzw = (const float*)d_in[4];
  const float* nzb = (const float*)d_in[5];
  const float* wm  = (const float*)d_in[6];
  const float* wg  = (const float*)d_in[7];
  const float* wz  = (const float*)d_in[8];
  const float* wo  = (const float*)d_in[9];
  float* out = (float*)d_out;

  char* ws = (char*)d_ws;
  size_t off = 0;
  auto alloc = [&](size_t bytes) -> void* {
    void* p = ws + off;
    off += (bytes + 1023) & ~(size_t)1023;
    return p;
  };
  float*          b_e  = (float*)alloc((size_t)768 * 8 * 768 * 4);          // 18.9 MB
  float*          Ms   = (float*)alloc((size_t)768 * 8 * 4);
  float*          invs = (float*)alloc((size_t)768 * 8 * 4);
  unsigned short* Awt  = (unsigned short*)alloc((size_t)8 * 768 * 768 * 2); // 9.4 MB
  unsigned short* WBT  = (unsigned short*)alloc((size_t)512 * 64 * 2);
  unsigned short* woT  = (unsigned short*)alloc((size_t)64 * 256 * 2);
  unsigned short* VT   = (unsigned short*)alloc((size_t)8 * 16384 * 768 * 2);  // 201 MB
  unsigned short* G    = (unsigned short*)alloc((size_t)512 * 768 * 256 * 2);  // 201 MB
  unsigned short* O    = (unsigned short*)alloc((size_t)512 * 768 * 256 * 2);  // 201 MB
  if (ws_size < off) return;  // workspace too small: fail loudly (zero output)

  k0_prep<<<128, 256, 0, stream>>>(wm, wg, wo, WBT, woT);
  k1_zln_b<<<dim3(24, 768), 256, 0, stream>>>(z, nzw, nzb, wz, b_e);
  k1b_softmax<<<6144, 256, 0, stream>>>(b_e, Ms, invs);
  k1b2_transpose<<<dim3(12, 12, 8), 256, 0, stream>>>(b_e, Ms, invs, Awt);
  k2_mln_vg<<<dim3(12, 64), 256, 0, stream>>>(m, nmw, nmb, WBT, VT, G);
  k3_gemm<<<dim3(768, 8), 256, 0, stream>>>(Awt, VT, O);
  k4_out<<<dim3(12, 64), 256, 0, stream>>>(O, G, woT, out);
}